// Round 16
// baseline (300.850 us; speedup 1.0000x reference)
//
#include <hip/hip_runtime.h>

// Problem constants
#define B_ 8
#define N_ 2048
#define T_ 12
#define F_ 64
#define NT 24576    // N_*T_
#define CH 192      // 3 * 64 output channels
#define C_ 768      // 64 * 12 rows per diffusion GEMM B-operand

typedef __bf16 bf16x8 __attribute__((ext_vector_type(8)));
typedef float f32x4 __attribute__((ext_vector_type(4)));
typedef float f32x16 __attribute__((ext_vector_type(16)));

typedef const __attribute__((address_space(1))) unsigned int as1_uint;
typedef __attribute__((address_space(3))) unsigned int as3_uint;

__device__ __forceinline__ void gload16(const void* g, void* l) {
  __builtin_amdgcn_global_load_lds((as1_uint*)g, (as3_uint*)l, 16, 0, 0);
}

__device__ __forceinline__ unsigned short f2bf(float f) {
  unsigned int u = __float_as_uint(f);
  u += 0x7FFFu + ((u >> 16) & 1u);   // RNE
  return (unsigned short)(u >> 16);
}

__device__ __forceinline__ float bf2f(unsigned short u) {
  return __uint_as_float(((unsigned int)u) << 16);
}

__device__ __forceinline__ float leaky(float v) {
  return v >= 0.0f ? v : 0.01f * v;
}

// ---------------------------------------------------------------------------
// convertAf_k: adj fp32 -> Af FRAGMENT-LINEAR bf16 for mfma_32x32x16 A-side,
// AND rs1[b][n] = rowsum(adj).
// Af[((b*64+ng)*128 + kg)*512 + lane*8 + j] = adj[b][ng*32+(l&31)][kg*16+(l>>5)*8+j]
// (A-frag layout verified by gemmB round-15 pass: row = l&31, k = (l>>5)*8+j.)
// grid (64 ng, 8 b), block 256 (4 waves; wave w covers kg = w, w+4, ...).
// ---------------------------------------------------------------------------
__global__ __launch_bounds__(256) void convertAf_k(const float* __restrict__ adj,
                                                   unsigned short* __restrict__ Af,
                                                   float* __restrict__ rs1) {
  const int tid = threadIdx.x;
  const int lane = tid & 63;
  const int wave = tid >> 6;
  const int ng = blockIdx.x;
  const int b  = blockIdx.y;
  const int row = ng * 32 + (lane & 31);

  const float* srcRow = adj + ((size_t)b * N_ + row) * N_ + (lane >> 5) * 8;
  unsigned short* dstB = Af + ((size_t)(b * 64 + ng) * 128) * 512 + lane * 8;

  float rsum = 0.0f;
#pragma unroll 4
  for (int kg = wave; kg < 128; kg += 4) {
    const float* s = srcRow + kg * 16;
    const float4 v0 = *reinterpret_cast<const float4*>(s);
    const float4 v1 = *reinterpret_cast<const float4*>(s + 4);
    rsum += v0.x + v0.y + v0.z + v0.w + v1.x + v1.y + v1.z + v1.w;
    ushort4 a, c;
    a.x = f2bf(v0.x); a.y = f2bf(v0.y); a.z = f2bf(v0.z); a.w = f2bf(v0.w);
    c.x = f2bf(v1.x); c.y = f2bf(v1.y); c.z = f2bf(v1.z); c.w = f2bf(v1.w);
    unsigned short* d = dstB + (size_t)kg * 512;
    *reinterpret_cast<ushort4*>(d) = a;
    *reinterpret_cast<ushort4*>(d + 4) = c;
  }
  // row-sum reduce: (l, l^32) pair then across 4 waves
  rsum += __shfl_xor(rsum, 32);
  __shared__ float red[4][32];
  if (lane < 32) red[wave][lane] = rsum;
  __syncthreads();
  if (tid < 32)
    rs1[((size_t)b << 11) + ng * 32 + tid] =
        red[0][tid] + red[1][tid] + red[2][tid] + red[3][tid];
}

// ---------------------------------------------------------------------------
// rs2_k: rs2 = A @ rs1, reading fragment-linear Af.
// grid (64 ng, 8 b), block 256; wave w covers kg = w, w+4, ...
// ---------------------------------------------------------------------------
__global__ __launch_bounds__(256) void rs2_k(const unsigned short* __restrict__ Af,
                                             const float* __restrict__ rs1,
                                             float* __restrict__ rs2) {
  const int tid = threadIdx.x;
  const int lane = tid & 63;
  const int wave = tid >> 6;
  const int ng = blockIdx.x;
  const int b  = blockIdx.y;

  const unsigned short* srcB = Af + ((size_t)(b * 64 + ng) * 128) * 512 + lane * 8;
  const float* r1b = rs1 + ((size_t)b << 11) + (lane >> 5) * 8;

  float s = 0.0f;
#pragma unroll 4
  for (int kg = wave; kg < 128; kg += 4) {
    const bf16x8 a = *reinterpret_cast<const bf16x8*>(srcB + (size_t)kg * 512);
    const float* r1 = r1b + kg * 16;
#pragma unroll
    for (int j = 0; j < 8; ++j) s += (float)a[j] * r1[j];
  }
  s += __shfl_xor(s, 32);
  __shared__ float red[4][32];
  if (lane < 32) red[wave][lane] = s;
  __syncthreads();
  if (tid < 32)
    rs2[((size_t)b << 11) + ng * 32 + tid] =
        red[0][tid] + red[1][tid] + red[2][tid] + red[3][tid];
}

// ---------------------------------------------------------------------------
// convertX_k: x fp32 [b][f][n][t] -> Xt bf16 [b][(f*12+t)][n].
// ---------------------------------------------------------------------------
__global__ __launch_bounds__(256) void convertX_k(const float* __restrict__ x,
                                                  unsigned short* __restrict__ Xt) {
  __shared__ float xl[T_][260];
  const int tid = threadIdx.x;
  const int n0 = blockIdx.x * 256;
  const int f = blockIdx.y;
  const int b = blockIdx.z;

  const float* src = x + (((size_t)b * F_ + f) * N_ + n0 + tid) * T_;
  float4 v0 = *reinterpret_cast<const float4*>(src);
  float4 v1 = *reinterpret_cast<const float4*>(src + 4);
  float4 v2 = *reinterpret_cast<const float4*>(src + 8);
  xl[0][tid] = v0.x;  xl[1][tid] = v0.y;  xl[2][tid] = v0.z;  xl[3][tid] = v0.w;
  xl[4][tid] = v1.x;  xl[5][tid] = v1.y;  xl[6][tid] = v1.z;  xl[7][tid] = v1.w;
  xl[8][tid] = v2.x;  xl[9][tid] = v2.y;  xl[10][tid] = v2.z; xl[11][tid] = v2.w;
  __syncthreads();
#pragma unroll
  for (int t = 0; t < T_; ++t)
    Xt[((size_t)b * C_ + f * T_ + t) * N_ + n0 + tid] = f2bf(xl[t][tid]);
}

// ---------------------------------------------------------------------------
// stage_wt + p0_k + pT_k (unchanged)
// ---------------------------------------------------------------------------
__device__ __forceinline__ void stage_wt(const float* __restrict__ W,
                                         unsigned short* Wt, int tid) {
  const int f = tid >> 2;
  const int q = tid & 3;
  const float4* row = reinterpret_cast<const float4*>(W + f * 64 + q * 16);
#pragma unroll
  for (int v4 = 0; v4 < 4; ++v4) {
    float4 v = row[v4];
    const int ob = q * 16 + v4 * 4;
    Wt[(ob + 0) * 72 + f] = f2bf(v.x);
    Wt[(ob + 1) * 72 + f] = f2bf(v.y);
    Wt[(ob + 2) * 72 + f] = f2bf(v.z);
    Wt[(ob + 3) * 72 + f] = f2bf(v.w);
  }
}

__global__ __launch_bounds__(256) void p0_k(const float* __restrict__ x,
                                            const float* __restrict__ W0,
                                            const float* __restrict__ bia0,
                                            float* __restrict__ out) {
  __shared__ unsigned short Wt[64 * 72];
  __shared__ float bias[64];
  const int tid = threadIdx.x;
  stage_wt(W0, Wt, tid);
  if (tid < 64) bias[tid] = bia0[tid];
  __syncthreads();

  const int lane = tid & 63;
  const int wave = tid >> 6;
  const int b = blockIdx.y;
  const int e = blockIdx.x * 64 + wave * 16 + (lane & 15);
  const int fgrp = (lane >> 4) * 8;
  const float* xb = x + (size_t)b * F_ * NT;

  bf16x8 xf[2];
#pragma unroll
  for (int kf = 0; kf < 2; ++kf)
#pragma unroll
    for (int j = 0; j < 8; ++j)
      xf[kf][j] = (__bf16)xb[(size_t)(fgrp + kf * 32 + j) * NT + e];

  float* outb = out + (size_t)b * CH * NT;
#pragma unroll
  for (int ob = 0; ob < 4; ++ob) {
    f32x4 acc = {};
#pragma unroll
    for (int kf = 0; kf < 2; ++kf) {
      bf16x8 af = *reinterpret_cast<const bf16x8*>(
          &Wt[(ob * 16 + (lane & 15)) * 72 + kf * 32 + fgrp]);
      acc = __builtin_amdgcn_mfma_f32_16x16x32_bf16(af, xf[kf], acc, 0, 0, 0);
    }
#pragma unroll
    for (int r = 0; r < 4; ++r) {
      const int o = ob * 16 + (lane >> 4) * 4 + r;
      outb[(size_t)o * NT + e] = leaky(acc[r] + bias[o]);
    }
  }
}

__global__ __launch_bounds__(256) void pT_k(const unsigned short* __restrict__ Yt,
                                            const float* __restrict__ W,
                                            const float* __restrict__ bia,
                                            const float* __restrict__ rs,
                                            float* __restrict__ out,
                                            const int ocb) {
  __shared__ unsigned short Wt[64 * 72];
  __shared__ float bias[64];
  const int tid = threadIdx.x;
  stage_wt(W, Wt, tid);
  if (tid < 64) bias[tid] = bia[tid];
  __syncthreads();

  const int lane = tid & 63;
  const int wave = tid >> 6;
  const int b = blockIdx.y;
  const int n = blockIdx.x * 16 + (lane & 15);
  const int fgrp = (lane >> 4) * 8;
  const __bf16* Yb = reinterpret_cast<const __bf16*>(Yt + (size_t)b * C_ * N_);
  const float rsv = rs[((size_t)b << 11) + n];
  float* outb = out + (size_t)b * CH * NT;

#pragma unroll
  for (int it = 0; it < 3; ++it) {
    const int t = wave * 3 + it;

    bf16x8 xf[2];
#pragma unroll
    for (int kf = 0; kf < 2; ++kf)
#pragma unroll
      for (int j = 0; j < 8; ++j)
        xf[kf][j] = Yb[(size_t)((kf * 32 + fgrp + j) * T_ + t) * N_ + n];

#pragma unroll
    for (int ob = 0; ob < 4; ++ob) {
      f32x4 acc = {};
#pragma unroll
      for (int kf = 0; kf < 2; ++kf) {
        bf16x8 af = *reinterpret_cast<const bf16x8*>(
            &Wt[(ob * 16 + (lane & 15)) * 72 + kf * 32 + fgrp]);
        acc = __builtin_amdgcn_mfma_f32_16x16x32_bf16(af, xf[kf], acc, 0, 0, 0);
      }
#pragma unroll
      for (int r = 0; r < 4; ++r) {
        const int o = ob * 16 + (lane >> 4) * 4 + r;
        outb[(size_t)(ocb + o) * NT + n * T_ + t] = leaky(acc[r] + rsv * bias[o]);
      }
    }
  }
}

// ---------------------------------------------------------------------------
// gemmS_k: A-STREAMED diffusion GEMM (32x32x16 MFMA).
// C[n][c] = sum_m adj[b][n][m] * Bt[b][c][m],  K = 2048, BK = 64.
// A comes from FRAGMENT-LINEAR Af: each A-frag = ONE 1KB coalesced
// global_load_dwordx4 per wave (no LDS, no barrier dependency; L2-served,
// panels shared by 4 co-XCD c-blocks). Only B (3MB/batch) staged in LDS.
// This attacks the measured pipe-sum: LDS traffic drops ~60%, staging
// traffic ~55% vs both-operand LDS kernels (rounds 5-15, all ~84 us).
//
// Tile 128x192, 4 waves (2M x 2N), wave 64x96 = acc[2][3] f32x16.
// B LDS: 2 x [192][64] shorts = 48KB static, double-buffered, ONE
// __syncthreads per K-tile (stage writes other buffer; compiler's
// vmcnt(0)-before-barrier completes it).
// B layout granule-XOR (verified 0-conflict): LDS(r,g) = global(r, g^(r&7));
// staging pre-swizzles per-lane GLOBAL granule (l&7)^(l>>3); reads use
// g_eff = (2s+hi)^(l&7).
// grid 512 = 8 b x (16 n x 4 c) -> 3 blocks/CU (144KB LDS, VGPR<=170 via
// launch_bounds(256,3)); blockIdx&7 = batch = XCD.
// Epilogue: Ht[c][n] bf16; C/D 32x32 layout col=lane&31,
// row=(reg&3)+8*(reg>>2)+4*(lane>>5).
// ---------------------------------------------------------------------------
__global__ __launch_bounds__(256, 3) void gemmS_k(
    const unsigned short* __restrict__ Af,
    const unsigned short* __restrict__ Bt,
    unsigned short* __restrict__ Ht)
{
  __shared__ __align__(16) unsigned short lds[2][12288];  // B dbuf, 48KB

  const int tid  = threadIdx.x;
  const int lane = tid & 63;
  const int wave = tid >> 6;     // 0..3
  const int wm = wave >> 1;      // 0..1  M half (64 rows)
  const int wn = wave & 1;       // 0..1  N half (96 cols)

  const int b  = blockIdx.x & 7;            // batch == XCD
  const int j  = blockIdx.x >> 3;           // 0..63
  const int n0 = (j & 15) * 128;
  const int c0 = (j >> 4) * 192;

  const unsigned short* Bm = Bt + (size_t)b * C_ * N_;

  // A stream pointers: frag-linear, ng = n0/32 + wm*2 + m
  const unsigned short* aP0 =
      Af + ((size_t)(b * 64 + (n0 >> 5) + wm * 2 + 0) * 128) * 512 + lane * 8;
  const unsigned short* aP1 =
      Af + ((size_t)(b * 64 + (n0 >> 5) + wm * 2 + 1) * 128) * 512 + lane * 8;

  // B staging: lane l -> row base+(l>>3), LDS granule l&7 (linear dest);
  // GLOBAL source granule pre-swizzled = (l&7)^(l>>3).
  const int swz = ((lane & 7) ^ (lane >> 3)) * 8;   // shorts
  const unsigned short* bSt = Bm + (size_t)(c0 + wave * 48 + (lane >> 3)) * N_ + swz;
  const int ldsW = wave * 3072;   // 48 rows * 64 shorts

  // B fragment read constants
  const int l31 = lane & 31;
  const int x7  = lane & 7;
  const int hi  = lane >> 5;
  const int sh  = (lane >> 1) & 3;
  const int e0  = hi ^ (x7 & 1);
  const int bBase = (wn * 96 + l31) * 64;   // + nf*2048 + g_eff*8

  f32x16 acc[2][3] = {};

#define STG(S, KT) \
  gload16(bSt + (KT) * 64,            lds[S] + ldsW); \
  gload16(bSt + 8 * N_ + (KT) * 64,   lds[S] + ldsW + 512); \
  gload16(bSt + 16 * N_ + (KT) * 64,  lds[S] + ldsW + 1024); \
  gload16(bSt + 24 * N_ + (KT) * 64,  lds[S] + ldsW + 1536); \
  gload16(bSt + 32 * N_ + (KT) * 64,  lds[S] + ldsW + 2048); \
  gload16(bSt + 40 * N_ + (KT) * 64,  lds[S] + ldsW + 2560);

  // ---- prologue: stage tile 0 -> buf0
  STG(0, 0)

#pragma unroll 1
  for (int kt = 0; kt < 32; ++kt) {
    __syncthreads();             // stage(kt) complete (vmcnt0 pre-barrier) & visible
    const int S = kt & 1;
    if (kt + 1 < 32) { STG((kt + 1) & 1, kt + 1) }
#pragma unroll
    for (int s = 0; s < 4; ++s) {
      const size_t kg = (size_t)(kt * 4 + s) * 512;
      bf16x8 af0 = *reinterpret_cast<const bf16x8*>(aP0 + kg);
      bf16x8 af1 = *reinterpret_cast<const bf16x8*>(aP1 + kg);
      const int ge = (((s ^ sh) << 1) | e0) * 8;
      bf16x8 bv0 = *(const bf16x8*)(lds[S] + bBase + 0 * 2048 + ge);
      bf16x8 bv1 = *(const bf16x8*)(lds[S] + bBase + 1 * 2048 + ge);
      bf16x8 bv2 = *(const bf16x8*)(lds[S] + bBase + 2 * 2048 + ge);
      acc[0][0] = __builtin_amdgcn_mfma_f32_32x32x16_bf16(af0, bv0, acc[0][0], 0, 0, 0);
      acc[0][1] = __builtin_amdgcn_mfma_f32_32x32x16_bf16(af0, bv1, acc[0][1], 0, 0, 0);
      acc[0][2] = __builtin_amdgcn_mfma_f32_32x32x16_bf16(af0, bv2, acc[0][2], 0, 0, 0);
      acc[1][0] = __builtin_amdgcn_mfma_f32_32x32x16_bf16(af1, bv0, acc[1][0], 0, 0, 0);
      acc[1][1] = __builtin_amdgcn_mfma_f32_32x32x16_bf16(af1, bv1, acc[1][1], 0, 0, 0);
      acc[1][2] = __builtin_amdgcn_mfma_f32_32x32x16_bf16(af1, bv2, acc[1][2], 0, 0, 0);
    }
  }

  // ---- epilogue: Ht[c][n] bf16. D frag (32x32): col = lane&31,
  // row = (reg&3) + 8*(reg>>2) + 4*(lane>>5)
  unsigned short* Hb = Ht + (size_t)b * C_ * N_;
#pragma unroll
  for (int m = 0; m < 2; ++m) {
#pragma unroll
    for (int nf = 0; nf < 3; ++nf) {
      const int c = c0 + wn * 96 + nf * 32 + l31;
#pragma unroll
      for (int q = 0; q < 4; ++q) {
        const int nb = n0 + wm * 64 + m * 32 + q * 8 + 4 * hi;
        ushort4 u;
        u.x = f2bf(acc[m][nf][q * 4 + 0]);
        u.y = f2bf(acc[m][nf][q * 4 + 1]);
        u.z = f2bf(acc[m][nf][q * 4 + 2]);
        u.w = f2bf(acc[m][nf][q * 4 + 3]);
        *reinterpret_cast<ushort4*>(&Hb[(size_t)c * N_ + nb]) = u;
      }
    }
  }
#undef STG
}

// ---------------------------------------------------------------------------
// Workspace layout (bytes):
//   Af  : [0, 67108864)            fragment-linear adj bf16
//   R1  : [67108864, 92274688)     Xt, then Y2t   (8*768*2048 bf16)
//   R2  : [92274688, 117440512)    Yt
//   rs1 : [117440512, 117506048)   8*2048 fp32
//   rs2 : [117506048, 117571584)   8*2048 fp32
// ---------------------------------------------------------------------------
extern "C" void kernel_launch(void* const* d_in, const int* in_sizes, int n_in,
                              void* d_out, int out_size, void* d_ws, size_t ws_size,
                              hipStream_t stream) {
  const float* x   = (const float*)d_in[0];
  const float* adj = (const float*)d_in[1];
  const float* W0  = (const float*)d_in[2];
  const float* b0  = (const float*)d_in[3];
  const float* W1  = (const float*)d_in[4];
  const float* b1  = (const float*)d_in[5];
  const float* W2  = (const float*)d_in[6];
  const float* b2  = (const float*)d_in[7];
  float* out = (float*)d_out;

  char* ws = (char*)d_ws;
  unsigned short* Af = (unsigned short*)ws;
  unsigned short* R1 = (unsigned short*)(ws + 67108864);   // Xt -> Y2t
  unsigned short* R2 = (unsigned short*)(ws + 92274688);   // Yt
  float* rs1 = (float*)(ws + 117440512);
  float* rs2 = (float*)(ws + 117506048);

  // 1) adj -> Af fragment-linear + rowsums rs1
  hipLaunchKernelGGL(convertAf_k, dim3(64, 8), dim3(256), 0, stream,
                     adj, Af, rs1);

  // 2) x -> Xt bf16 [(f,t)][n]
  hipLaunchKernelGGL(convertX_k, dim3(N_ / 256, F_, B_), dim3(256), 0, stream,
                     x, R1);

  // 3) p=0: out[0:64) = leaky(x.W0 + b0)
  hipLaunchKernelGGL(p0_k, dim3(NT / 64, B_), dim3(256), 0, stream,
                     x, W0, b0, out);

  // 4) Yt = (A @ X)^T
  hipLaunchKernelGGL(gemmS_k, dim3(512), dim3(256), 0, stream,
                     Af, R1, R2);

  // 5) rs2 = A @ rs1
  hipLaunchKernelGGL(rs2_k, dim3(64, 8), dim3(256), 0, stream,
                     Af, rs1, rs2);

  // 6) p=1: out[64:128) = leaky(Y.W1 + rs1*b1)
  hipLaunchKernelGGL(pT_k, dim3(N_ / 16, B_), dim3(256), 0, stream,
                     R2, W1, b1, rs1, out, 64);

  // 7) Y2t = (A @ Y)^T
  hipLaunchKernelGGL(gemmS_k, dim3(512), dim3(256), 0, stream,
                     Af, R2, R1);

  // 8) p=2: out[128:192) = leaky(Y2.W2 + rs2*b2)
  hipLaunchKernelGGL(pT_k, dim3(N_ / 16, B_), dim3(256), 0, stream,
                     R1, W2, b2, rs2, out, 128);
}

// Round 17
// 276.008 us; speedup vs baseline: 1.0900x; 1.0900x over previous
//
#include <hip/hip_runtime.h>

// Problem constants
#define B_ 8
#define N_ 2048
#define T_ 12
#define F_ 64
#define NT 24576    // N_*T_
#define CH 192      // 3 * 64 output channels
#define C_ 768      // 64 * 12 rows per diffusion GEMM B-operand

typedef __bf16 bf16x8 __attribute__((ext_vector_type(8)));
typedef float f32x4 __attribute__((ext_vector_type(4)));

typedef const __attribute__((address_space(1))) unsigned int as1_uint;
typedef __attribute__((address_space(3))) unsigned int as3_uint;

__device__ __forceinline__ void gload16(const void* g, void* l) {
  __builtin_amdgcn_global_load_lds((as1_uint*)g, (as3_uint*)l, 16, 0, 0);
}

__device__ __forceinline__ unsigned short f2bf(float f) {
  unsigned int u = __float_as_uint(f);
  u += 0x7FFFu + ((u >> 16) & 1u);   // RNE
  return (unsigned short)(u >> 16);
}

__device__ __forceinline__ float bf2f(unsigned short u) {
  return __uint_as_float(((unsigned int)u) << 16);
}

__device__ __forceinline__ float leaky(float v) {
  return v >= 0.0f ? v : 0.01f * v;
}

// ---------------------------------------------------------------------------
// convert_rs_k: adj fp32 -> adjb bf16 (row-major) AND rs1[b][n] = rowsum(adj).
// ---------------------------------------------------------------------------
__global__ __launch_bounds__(256) void convert_rs_k(const float* __restrict__ adj,
                                                    unsigned short* __restrict__ adjb,
                                                    float* __restrict__ rs1) {
  const int row = blockIdx.x;               // b*2048 + n
  const int tid = threadIdx.x;
  const int lane = tid & 63;
  const int wave = tid >> 6;
  const float4* src = reinterpret_cast<const float4*>(adj + (size_t)row * N_);
  ushort4* dst = reinterpret_cast<ushort4*>(adjb + (size_t)row * N_);

  float s = 0.0f;
#pragma unroll
  for (int i = tid; i < 512; i += 256) {
    const float4 v = src[i];
    ushort4 u;
    u.x = f2bf(v.x); u.y = f2bf(v.y); u.z = f2bf(v.z); u.w = f2bf(v.w);
    dst[i] = u;
    s += v.x + v.y + v.z + v.w;
  }
#pragma unroll
  for (int o = 32; o; o >>= 1) s += __shfl_xor(s, o);
  __shared__ float red[4];
  if (lane == 0) red[wave] = s;
  __syncthreads();
  if (tid == 0) rs1[row] = red[0] + red[1] + red[2] + red[3];
}

// ---------------------------------------------------------------------------
// rs2_k: rs2 = adjb @ rs1 (per-batch GEMV).
// ---------------------------------------------------------------------------
__global__ __launch_bounds__(256) void rs2_k(const unsigned short* __restrict__ adjb,
                                             const float* __restrict__ rs1,
                                             float* __restrict__ rs2) {
  const int row = blockIdx.x;
  const int b = row >> 11;
  const int tid = threadIdx.x;
  const int lane = tid & 63;
  const int wave = tid >> 6;
  const ushort4* src = reinterpret_cast<const ushort4*>(adjb + (size_t)row * N_);
  const float* r1 = rs1 + ((size_t)b << 11);

  float s = 0.0f;
#pragma unroll
  for (int i = tid; i < 512; i += 256) {
    const ushort4 a = src[i];
    const int m = i * 4;
    s += bf2f(a.x) * r1[m] + bf2f(a.y) * r1[m + 1]
       + bf2f(a.z) * r1[m + 2] + bf2f(a.w) * r1[m + 3];
  }
#pragma unroll
  for (int o = 32; o; o >>= 1) s += __shfl_xor(s, o);
  __shared__ float red[4];
  if (lane == 0) red[wave] = s;
  __syncthreads();
  if (tid == 0) rs2[row] = red[0] + red[1] + red[2] + red[3];
}

// ---------------------------------------------------------------------------
// convertX_k: x fp32 [b][f][n][t] -> Xt bf16 [b][(f*12+t)][n].
// The ONLY reader of x (402 MB): p=0 transform now reads Xt (50 MB) instead.
// ---------------------------------------------------------------------------
__global__ __launch_bounds__(256) void convertX_k(const float* __restrict__ x,
                                                  unsigned short* __restrict__ Xt) {
  __shared__ float xl[T_][260];
  const int tid = threadIdx.x;
  const int n0 = blockIdx.x * 256;
  const int f = blockIdx.y;
  const int b = blockIdx.z;

  const float* src = x + (((size_t)b * F_ + f) * N_ + n0 + tid) * T_;
  float4 v0 = *reinterpret_cast<const float4*>(src);
  float4 v1 = *reinterpret_cast<const float4*>(src + 4);
  float4 v2 = *reinterpret_cast<const float4*>(src + 8);
  xl[0][tid] = v0.x;  xl[1][tid] = v0.y;  xl[2][tid] = v0.z;  xl[3][tid] = v0.w;
  xl[4][tid] = v1.x;  xl[5][tid] = v1.y;  xl[6][tid] = v1.z;  xl[7][tid] = v1.w;
  xl[8][tid] = v2.x;  xl[9][tid] = v2.y;  xl[10][tid] = v2.z; xl[11][tid] = v2.w;
  __syncthreads();
#pragma unroll
  for (int t = 0; t < T_; ++t)
    Xt[((size_t)b * C_ + f * T_ + t) * N_ + n0 + tid] = f2bf(xl[t][tid]);
}

// ---------------------------------------------------------------------------
// stage_wt: W [64 f][64 o] fp32 -> Wt[o][f] bf16 (rows padded to 72) in LDS.
// ---------------------------------------------------------------------------
__device__ __forceinline__ void stage_wt(const float* __restrict__ W,
                                         unsigned short* Wt, int tid) {
  const int f = tid >> 2;
  const int q = tid & 3;
  const float4* row = reinterpret_cast<const float4*>(W + f * 64 + q * 16);
#pragma unroll
  for (int v4 = 0; v4 < 4; ++v4) {
    float4 v = row[v4];
    const int ob = q * 16 + v4 * 4;
    Wt[(ob + 0) * 72 + f] = f2bf(v.x);
    Wt[(ob + 1) * 72 + f] = f2bf(v.y);
    Wt[(ob + 2) * 72 + f] = f2bf(v.z);
    Wt[(ob + 3) * 72 + f] = f2bf(v.w);
  }
}

// ---------------------------------------------------------------------------
// pT_k: out[ocb..ocb+64) = leaky(Y.W + rs*b), Y given as Yt bf16 [(f*12+t)][n].
// rs == nullptr means rs === 1.0 (used for the p=0 path reading Xt).
// Block: 16 n x all 12 t; wave w handles t = w*3..w*3+2.  grid (128, 8).
// ---------------------------------------------------------------------------
__global__ __launch_bounds__(256) void pT_k(const unsigned short* __restrict__ Yt,
                                            const float* __restrict__ W,
                                            const float* __restrict__ bia,
                                            const float* __restrict__ rs,
                                            float* __restrict__ out,
                                            const int ocb) {
  __shared__ unsigned short Wt[64 * 72];
  __shared__ float bias[64];
  const int tid = threadIdx.x;
  stage_wt(W, Wt, tid);
  if (tid < 64) bias[tid] = bia[tid];
  __syncthreads();

  const int lane = tid & 63;
  const int wave = tid >> 6;
  const int b = blockIdx.y;
  const int n = blockIdx.x * 16 + (lane & 15);
  const int fgrp = (lane >> 4) * 8;
  const __bf16* Yb = reinterpret_cast<const __bf16*>(Yt + (size_t)b * C_ * N_);
  const float rsv = rs ? rs[((size_t)b << 11) + n] : 1.0f;
  float* outb = out + (size_t)b * CH * NT;

#pragma unroll
  for (int it = 0; it < 3; ++it) {
    const int t = wave * 3 + it;

    bf16x8 xf[2];
#pragma unroll
    for (int kf = 0; kf < 2; ++kf)
#pragma unroll
      for (int j = 0; j < 8; ++j)
        xf[kf][j] = Yb[(size_t)((kf * 32 + fgrp + j) * T_ + t) * N_ + n];

#pragma unroll
    for (int ob = 0; ob < 4; ++ob) {
      f32x4 acc = {};
#pragma unroll
      for (int kf = 0; kf < 2; ++kf) {
        bf16x8 af = *reinterpret_cast<const bf16x8*>(
            &Wt[(ob * 16 + (lane & 15)) * 72 + kf * 32 + fgrp]);
        acc = __builtin_amdgcn_mfma_f32_16x16x32_bf16(af, xf[kf], acc, 0, 0, 0);
      }
#pragma unroll
      for (int r = 0; r < 4; ++r) {
        const int o = ob * 16 + (lane >> 4) * 4 + r;
        outb[(size_t)(ocb + o) * NT + n * T_ + t] = leaky(acc[r] + rsv * bias[o]);
      }
    }
  }
}

// ---------------------------------------------------------------------------
// gemmF_k (round-14 best, verbatim): 128x96 tile, BK=64, 4 waves, single
// 28KB static LDS, 2 __syncthreads per K-step, 4 blocks/CU TLP.
// C[n][c] = sum_m adj[b][n][m] * Bt[b][c][m]; writes Ht[c][n] bf16.
// LDS granule-XOR conflict-free; grid 1024 = 8 b x (16 n x 8 c).
// ---------------------------------------------------------------------------
__global__ __launch_bounds__(256, 4) void gemmF_k(
    const unsigned short* __restrict__ adjb,
    const unsigned short* __restrict__ Bt,
    unsigned short* __restrict__ Ht)
{
  __shared__ __align__(16) unsigned short lds[14336];  // A[128][64] + B[96][64]

  const int tid  = threadIdx.x;
  const int lane = tid & 63;
  const int wave = tid >> 6;     // 0..3
  const int wm = wave >> 1;      // 0..1  M half (64 rows)
  const int wn = wave & 1;       // 0..1  N half (48 cols)

  const int b  = blockIdx.x & 7;            // batch == XCD
  const int j  = blockIdx.x >> 3;           // 0..127
  const int n0 = (j & 15) * 128;
  const int c0 = (j >> 4) * 96;

  const unsigned short* A  = adjb + (size_t)b * N_ * N_;
  const unsigned short* Bm = Bt   + (size_t)b * C_ * N_;

  const int swz = ((lane & 7) ^ (lane >> 3)) * 8;   // shorts
  const unsigned short* aSt = A + (size_t)(n0 + wave * 32 + (lane >> 3)) * N_ + swz;
  const unsigned short* bSt = Bm + (size_t)(c0 + wave * 24 + (lane >> 3)) * N_ + swz;

  const int lr15 = lane & 15;
  const int x7   = lane & 7;
  const int aBase = (wm * 64 + lr15) * 64;          // + m*1024 + g*8
  const int bBase = 8192 + (wn * 48 + lr15) * 64;   // + nf*1024 + g*8

  f32x4 acc[4][3] = {};

#define STG(KT) \
  gload16(aSt + (KT) * 64,            lds + wave * 2048); \
  gload16(aSt + 8 * N_ + (KT) * 64,   lds + wave * 2048 + 512); \
  gload16(aSt + 16 * N_ + (KT) * 64,  lds + wave * 2048 + 1024); \
  gload16(aSt + 24 * N_ + (KT) * 64,  lds + wave * 2048 + 1536); \
  gload16(bSt + (KT) * 64,            lds + 8192 + wave * 1536); \
  gload16(bSt + 8 * N_ + (KT) * 64,   lds + 8192 + wave * 1536 + 512); \
  gload16(bSt + 16 * N_ + (KT) * 64,  lds + 8192 + wave * 1536 + 1024);

  // ---- prologue: stage tile 0
  STG(0)

#pragma unroll 1
  for (int kt = 0; kt < 32; ++kt) {
    __syncthreads();             // tile kt staged (vmcnt drained) & visible
#pragma unroll
    for (int kk = 0; kk < 2; ++kk) {
      const int g = ((kk * 4 + (lane >> 4)) ^ x7) * 8;
      bf16x8 af[4], bfv[3];
#pragma unroll
      for (int m = 0; m < 4; ++m)
        af[m] = *(const bf16x8*)(lds + aBase + m * 1024 + g);
#pragma unroll
      for (int nf = 0; nf < 3; ++nf)
        bfv[nf] = *(const bf16x8*)(lds + bBase + nf * 1024 + g);
#pragma unroll
      for (int m = 0; m < 4; ++m)
#pragma unroll
        for (int nf = 0; nf < 3; ++nf)
          acc[m][nf] = __builtin_amdgcn_mfma_f32_16x16x32_bf16(
              af[m], bfv[nf], acc[m][nf], 0, 0, 0);
    }
    __syncthreads();             // all waves done reading tile kt
    if (kt + 1 < 32) { STG(kt + 1) }
  }

  // ---- epilogue: Ht[c][n] bf16. D frag: col=lane&15, row=(lane>>4)*4+reg
  const int r4 = (lane >> 4) * 4;
  unsigned short* Hb = Ht + (size_t)b * C_ * N_;
#pragma unroll
  for (int m = 0; m < 4; ++m) {
#pragma unroll
    for (int nf = 0; nf < 3; ++nf) {
      const int c = c0 + wn * 48 + nf * 16 + lr15;
      const int nb = n0 + wm * 64 + m * 16 + r4;
      ushort4 u;
      u.x = f2bf(acc[m][nf][0]);
      u.y = f2bf(acc[m][nf][1]);
      u.z = f2bf(acc[m][nf][2]);
      u.w = f2bf(acc[m][nf][3]);
      *reinterpret_cast<ushort4*>(&Hb[(size_t)c * N_ + nb]) = u;
    }
  }
#undef STG
}

// ---------------------------------------------------------------------------
// Workspace layout (bytes):
//   adjb : [0, 67108864)            8*2048*2048 bf16
//   R1   : [67108864, 92274688)     Xt, then Y2t   (8*768*2048 bf16)
//   R2   : [92274688, 117440512)    Yt
//   rs1  : [117440512, 117506048)   8*2048 fp32
//   rs2  : [117506048, 117571584)   8*2048 fp32
// ---------------------------------------------------------------------------
extern "C" void kernel_launch(void* const* d_in, const int* in_sizes, int n_in,
                              void* d_out, int out_size, void* d_ws, size_t ws_size,
                              hipStream_t stream) {
  const float* x   = (const float*)d_in[0];
  const float* adj = (const float*)d_in[1];
  const float* W0  = (const float*)d_in[2];
  const float* b0  = (const float*)d_in[3];
  const float* W1  = (const float*)d_in[4];
  const float* b1  = (const float*)d_in[5];
  const float* W2  = (const float*)d_in[6];
  const float* b2  = (const float*)d_in[7];
  float* out = (float*)d_out;

  char* ws = (char*)d_ws;
  unsigned short* adjb = (unsigned short*)ws;
  unsigned short* R1   = (unsigned short*)(ws + 67108864);   // Xt -> Y2t
  unsigned short* R2   = (unsigned short*)(ws + 92274688);   // Yt
  float* rs1 = (float*)(ws + 117440512);
  float* rs2 = (float*)(ws + 117506048);

  // 1) adj -> bf16 + rowsums rs1
  hipLaunchKernelGGL(convert_rs_k, dim3(B_ * N_), dim3(256), 0, stream,
                     adj, adjb, rs1);

  // 2) x -> Xt bf16 [(f,t)][n]   (the ONLY read of x)
  hipLaunchKernelGGL(convertX_k, dim3(N_ / 256, F_, B_), dim3(256), 0, stream,
                     x, R1);

  // 3) p=0: out[0:64) = leaky(X.W0 + b0)  -- from Xt, rs=1
  hipLaunchKernelGGL(pT_k, dim3(N_ / 16, B_), dim3(256), 0, stream,
                     R1, W0, b0, (const float*)nullptr, out, 0);

  // 4) Yt = (A @ X)^T
  hipLaunchKernelGGL(gemmF_k, dim3(1024), dim3(256), 0, stream,
                     adjb, R1, R2);

  // 5) rs2 = A @ rs1
  hipLaunchKernelGGL(rs2_k, dim3(B_ * N_), dim3(256), 0, stream,
                     adjb, rs1, rs2);

  // 6) p=1: out[64:128) = leaky(Y.W1 + rs1*b1)
  hipLaunchKernelGGL(pT_k, dim3(N_ / 16, B_), dim3(256), 0, stream,
                     R2, W1, b1, rs1, out, 64);

  // 7) Y2t = (A @ Y)^T
  hipLaunchKernelGGL(gemmF_k, dim3(1024), dim3(256), 0, stream,
                     adjb, R2, R1);

  // 8) p=2: out[128:192) = leaky(Y2.W2 + rs2*b2)
  hipLaunchKernelGGL(pT_k, dim3(N_ / 16, B_), dim3(256), 0, stream,
                     R1, W2, b2, rs2, out, 128);
}

// Round 18
// 273.471 us; speedup vs baseline: 1.1001x; 1.0093x over previous
//
#include <hip/hip_runtime.h>

// Problem constants
#define B_ 8
#define N_ 2048
#define T_ 12
#define F_ 64
#define NT 24576    // N_*T_
#define CH 192      // 3 * 64 output channels
#define C_ 768      // 64 * 12 rows per diffusion GEMM B-operand

typedef __bf16 bf16x8 __attribute__((ext_vector_type(8)));
typedef float f32x4 __attribute__((ext_vector_type(4)));

typedef const __attribute__((address_space(1))) unsigned int as1_uint;
typedef __attribute__((address_space(3))) unsigned int as3_uint;

__device__ __forceinline__ void gload16(const void* g, void* l) {
  __builtin_amdgcn_global_load_lds((as1_uint*)g, (as3_uint*)l, 16, 0, 0);
}

__device__ __forceinline__ unsigned short f2bf(float f) {
  unsigned int u = __float_as_uint(f);
  u += 0x7FFFu + ((u >> 16) & 1u);   // RNE
  return (unsigned short)(u >> 16);
}

__device__ __forceinline__ float bf2f(unsigned short u) {
  return __uint_as_float(((unsigned int)u) << 16);
}

__device__ __forceinline__ float leaky(float v) {
  return v >= 0.0f ? v : 0.01f * v;
}

// ---------------------------------------------------------------------------
// convert_rs_k: adj fp32 -> adjb bf16 (row-major) AND rs1[b][n] = rowsum(adj).
// ---------------------------------------------------------------------------
__global__ __launch_bounds__(256) void convert_rs_k(const float* __restrict__ adj,
                                                    unsigned short* __restrict__ adjb,
                                                    float* __restrict__ rs1) {
  const int row = blockIdx.x;               // b*2048 + n
  const int tid = threadIdx.x;
  const int lane = tid & 63;
  const int wave = tid >> 6;
  const float4* src = reinterpret_cast<const float4*>(adj + (size_t)row * N_);
  ushort4* dst = reinterpret_cast<ushort4*>(adjb + (size_t)row * N_);

  float s = 0.0f;
#pragma unroll
  for (int i = tid; i < 512; i += 256) {
    const float4 v = src[i];
    ushort4 u;
    u.x = f2bf(v.x); u.y = f2bf(v.y); u.z = f2bf(v.z); u.w = f2bf(v.w);
    dst[i] = u;
    s += v.x + v.y + v.z + v.w;
  }
#pragma unroll
  for (int o = 32; o; o >>= 1) s += __shfl_xor(s, o);
  __shared__ float red[4];
  if (lane == 0) red[wave] = s;
  __syncthreads();
  if (tid == 0) rs1[row] = red[0] + red[1] + red[2] + red[3];
}

// ---------------------------------------------------------------------------
// rs2_k: rs2 = adjb @ rs1 (per-batch GEMV).
// ---------------------------------------------------------------------------
__global__ __launch_bounds__(256) void rs2_k(const unsigned short* __restrict__ adjb,
                                             const float* __restrict__ rs1,
                                             float* __restrict__ rs2) {
  const int row = blockIdx.x;
  const int b = row >> 11;
  const int tid = threadIdx.x;
  const int lane = tid & 63;
  const int wave = tid >> 6;
  const ushort4* src = reinterpret_cast<const ushort4*>(adjb + (size_t)row * N_);
  const float* r1 = rs1 + ((size_t)b << 11);

  float s = 0.0f;
#pragma unroll
  for (int i = tid; i < 512; i += 256) {
    const ushort4 a = src[i];
    const int m = i * 4;
    s += bf2f(a.x) * r1[m] + bf2f(a.y) * r1[m + 1]
       + bf2f(a.z) * r1[m + 2] + bf2f(a.w) * r1[m + 3];
  }
#pragma unroll
  for (int o = 32; o; o >>= 1) s += __shfl_xor(s, o);
  __shared__ float red[4];
  if (lane == 0) red[wave] = s;
  __syncthreads();
  if (tid == 0) rs2[row] = red[0] + red[1] + red[2] + red[3];
}

// ---------------------------------------------------------------------------
// convertX_k: x fp32 [b][f][n][t] -> Xt bf16 [b][(f*12+t)][n].
// ---------------------------------------------------------------------------
__global__ __launch_bounds__(256) void convertX_k(const float* __restrict__ x,
                                                  unsigned short* __restrict__ Xt) {
  __shared__ float xl[T_][260];
  const int tid = threadIdx.x;
  const int n0 = blockIdx.x * 256;
  const int f = blockIdx.y;
  const int b = blockIdx.z;

  const float* src = x + (((size_t)b * F_ + f) * N_ + n0 + tid) * T_;
  float4 v0 = *reinterpret_cast<const float4*>(src);
  float4 v1 = *reinterpret_cast<const float4*>(src + 4);
  float4 v2 = *reinterpret_cast<const float4*>(src + 8);
  xl[0][tid] = v0.x;  xl[1][tid] = v0.y;  xl[2][tid] = v0.z;  xl[3][tid] = v0.w;
  xl[4][tid] = v1.x;  xl[5][tid] = v1.y;  xl[6][tid] = v1.z;  xl[7][tid] = v1.w;
  xl[8][tid] = v2.x;  xl[9][tid] = v2.y;  xl[10][tid] = v2.z; xl[11][tid] = v2.w;
  __syncthreads();
#pragma unroll
  for (int t = 0; t < T_; ++t)
    Xt[((size_t)b * C_ + f * T_ + t) * N_ + n0 + tid] = f2bf(xl[t][tid]);
}

// ---------------------------------------------------------------------------
// stage_wt: W [64 f][64 o] fp32 -> Wt[o][f] bf16 (rows padded to 72) in LDS.
// ---------------------------------------------------------------------------
__device__ __forceinline__ void stage_wt(const float* __restrict__ W,
                                         unsigned short* Wt, int tid) {
  const int f = tid >> 2;
  const int q = tid & 3;
  const float4* row = reinterpret_cast<const float4*>(W + f * 64 + q * 16);
#pragma unroll
  for (int v4 = 0; v4 < 4; ++v4) {
    float4 v = row[v4];
    const int ob = q * 16 + v4 * 4;
    Wt[(ob + 0) * 72 + f] = f2bf(v.x);
    Wt[(ob + 1) * 72 + f] = f2bf(v.y);
    Wt[(ob + 2) * 72 + f] = f2bf(v.z);
    Wt[(ob + 3) * 72 + f] = f2bf(v.w);
  }
}

// ---------------------------------------------------------------------------
// pT_k: out[ocb..ocb+64) = leaky(Y.W + rs*b), Y given as Yt bf16 [(f*12+t)][n].
// rs == nullptr means rs === 1.0 (used for the p=0 path reading Xt).
// ---------------------------------------------------------------------------
__global__ __launch_bounds__(256) void pT_k(const unsigned short* __restrict__ Yt,
                                            const float* __restrict__ W,
                                            const float* __restrict__ bia,
                                            const float* __restrict__ rs,
                                            float* __restrict__ out,
                                            const int ocb) {
  __shared__ unsigned short Wt[64 * 72];
  __shared__ float bias[64];
  const int tid = threadIdx.x;
  stage_wt(W, Wt, tid);
  if (tid < 64) bias[tid] = bia[tid];
  __syncthreads();

  const int lane = tid & 63;
  const int wave = tid >> 6;
  const int b = blockIdx.y;
  const int n = blockIdx.x * 16 + (lane & 15);
  const int fgrp = (lane >> 4) * 8;
  const __bf16* Yb = reinterpret_cast<const __bf16*>(Yt + (size_t)b * C_ * N_);
  const float rsv = rs ? rs[((size_t)b << 11) + n] : 1.0f;
  float* outb = out + (size_t)b * CH * NT;

#pragma unroll
  for (int it = 0; it < 3; ++it) {
    const int t = wave * 3 + it;

    bf16x8 xf[2];
#pragma unroll
    for (int kf = 0; kf < 2; ++kf)
#pragma unroll
      for (int j = 0; j < 8; ++j)
        xf[kf][j] = Yb[(size_t)((kf * 32 + fgrp + j) * T_ + t) * N_ + n];

#pragma unroll
    for (int ob = 0; ob < 4; ++ob) {
      f32x4 acc = {};
#pragma unroll
      for (int kf = 0; kf < 2; ++kf) {
        bf16x8 af = *reinterpret_cast<const bf16x8*>(
            &Wt[(ob * 16 + (lane & 15)) * 72 + kf * 32 + fgrp]);
        acc = __builtin_amdgcn_mfma_f32_16x16x32_bf16(af, xf[kf], acc, 0, 0, 0);
      }
#pragma unroll
      for (int r = 0; r < 4; ++r) {
        const int o = ob * 16 + (lane >> 4) * 4 + r;
        outb[(size_t)(ocb + o) * NT + n * T_ + t] = leaky(acc[r] + rsv * bias[o]);
      }
    }
  }
}

// ---------------------------------------------------------------------------
// gemm8_k (ROUND-4 VERBATIM — best measured GEMM, ~70 us/pass):
// 256x192 tile, BK=64 (2 kh planes of 32), 8 waves (2M x 4N), acc[8][3],
// 8 phases of 12 MFMA per K-tile pair, counted vmcnt(8) every other phase.
// LDS 128KB dynamic: A buf0/buf1, B buf0/buf1, planes [2 kh][256 r][32 sh],
// granule-XOR conflict-free. grid 256 = 8 b x (8 n x 4 c); blockIdx&7 = XCD.
// mode 1: Ht[c][n] = bf16(C) (transposed; feeds pT and the next GEMM).
// ---------------------------------------------------------------------------
__global__ __launch_bounds__(512, 2) void gemm8_k(
    const unsigned short* __restrict__ adjb,
    const unsigned short* __restrict__ Bt,
    float* __restrict__ out,
    unsigned short* __restrict__ Ht,
    const int mode, const int ochan_base)
{
  extern __shared__ __align__(16) unsigned short lds[];  // 65536 shorts = 128KB

  const int tid  = threadIdx.x;
  const int lane = tid & 63;
  const int wave = tid >> 6;
  const int wr = wave >> 2;      // 0..1  (M half, 128 rows)
  const int wc = wave & 3;       // 0..3  (N quarter, 48 cols)

  const int b  = blockIdx.x & 7;            // batch == XCD (round-robin)
  const int w  = blockIdx.x >> 3;           // 0..31
  const int n0 = (w & 7) * 256;
  const int c0 = (w >> 3) * 192;

  const unsigned short* A  = adjb + (size_t)b * N_ * N_;
  const unsigned short* Bm = Bt   + (size_t)b * C_ * N_;

  const int swzSrc = ((lane & 3) ^ ((lane >> 3) & 3)) * 8;   // shorts
  const unsigned short* aSt1 = A + (size_t)(n0 + wave * 16 + (lane >> 2)) * N_ + swzSrc;
  const unsigned short* aSt2 = aSt1 + (size_t)128 * N_;
  const unsigned short* bSt1 = Bm + (size_t)(c0 + wave * 16 + (lane >> 2)) * N_ + swzSrc;
  const int brow2 = c0 + 128 + wave * 16 + (lane >> 2);
  const unsigned short* bSt2 = Bm + (size_t)(brow2 < C_ ? brow2 : C_ - 1) * N_ + swzSrc;
  const int ldsW = wave * 512;

  const int kg  = (lane >> 4) ^ ((lane >> 1) & 3);
  const int aRd = (wr * 128 + (lane & 15)) * 32 + kg * 8;
  const int bRd = (wc * 48  + (lane & 15)) * 32 + kg * 8;

  f32x4 acc[8][3] = {};
  bf16x8 afr[4], bfr[3];

#define STGA(LDSB, KT, KH) \
  gload16(aSt1 + (KT) * 64 + (KH) * 32, lds + (LDSB) + (KH) * 8192 + ldsW); \
  gload16(aSt2 + (KT) * 64 + (KH) * 32, lds + (LDSB) + (KH) * 8192 + ldsW + 4096);

#define STGB(LDSB, KT, KH) \
  gload16(bSt1 + (KT) * 64 + (KH) * 32, lds + (LDSB) + (KH) * 8192 + ldsW); \
  gload16(bSt2 + (KT) * 64 + (KH) * 32, lds + (LDSB) + (KH) * 8192 + ldsW + 4096);

#define RD_B(BUFB, KH) { \
  _Pragma("unroll") \
  for (int nf = 0; nf < 3; ++nf) \
    bfr[nf] = *(const bf16x8*)(lds + (BUFB) + (KH) * 8192 + nf * 512 + bRd); }

#define RD_A(BUFA, KH, QM) { \
  _Pragma("unroll") \
  for (int mm = 0; mm < 4; ++mm) \
    afr[mm] = *(const bf16x8*)(lds + (BUFA) + (KH) * 8192 + (QM) * 2048 + mm * 512 + aRd); }

#define MFMA12(QM) { \
  _Pragma("unroll") \
  for (int mm = 0; mm < 4; ++mm) \
  _Pragma("unroll") \
  for (int nf = 0; nf < 3; ++nf) \
    acc[(QM) * 4 + mm][nf] = __builtin_amdgcn_mfma_f32_16x16x32_bf16( \
        afr[mm], bfr[nf], acc[(QM) * 4 + mm][nf], 0, 0, 0); }

#define MIDBAR() \
  __builtin_amdgcn_s_barrier(); \
  asm volatile("s_waitcnt lgkmcnt(0)" ::: "memory"); \
  __builtin_amdgcn_sched_barrier(0); \
  __builtin_amdgcn_s_setprio(1);

#define ENDBAR() \
  __builtin_amdgcn_s_setprio(0); \
  __builtin_amdgcn_s_barrier();

#define WAITV_(N) asm volatile("s_waitcnt vmcnt(" #N ")" ::: "memory");
#define WAITV(N) WAITV_(N)

  // ---- prologue: stage (0)kh0 A,B ; (0)kh1 A,B ; (1)kh0 A,B  (12 loads)
  STGA(0, 0, 0)      STGB(32768, 0, 0)
  STGA(0, 0, 1)      STGB(32768, 0, 1)
  STGA(16384, 1, 0)  STGB(49152, 1, 0)
  WAITV(8)
  __builtin_amdgcn_s_barrier();

  // ---- main loop: iterations 0..14 (K-tiles 0..29)
#pragma unroll 1
  for (int it = 0; it < 15; ++it) {
    const int kt0 = 2 * it;
    RD_B(32768, 0) RD_A(0, 0, 0)
    STGA(16384, kt0 + 1, 1)
    MIDBAR() MFMA12(0) ENDBAR()
    RD_A(0, 0, 1)
    STGB(49152, kt0 + 1, 1)
    WAITV(8)
    MIDBAR() MFMA12(1) ENDBAR()
    RD_B(32768, 1) RD_A(0, 1, 0)
    STGA(0, kt0 + 2, 0)
    MIDBAR() MFMA12(0) ENDBAR()
    RD_A(0, 1, 1)
    STGB(32768, kt0 + 2, 0)
    WAITV(8)
    MIDBAR() MFMA12(1) ENDBAR()
    RD_B(49152, 0) RD_A(16384, 0, 0)
    STGA(0, kt0 + 2, 1)
    MIDBAR() MFMA12(0) ENDBAR()
    RD_A(16384, 0, 1)
    STGB(32768, kt0 + 2, 1)
    WAITV(8)
    MIDBAR() MFMA12(1) ENDBAR()
    RD_B(49152, 1) RD_A(16384, 1, 0)
    STGA(16384, kt0 + 3, 0)
    MIDBAR() MFMA12(0) ENDBAR()
    RD_A(16384, 1, 1)
    STGB(49152, kt0 + 3, 0)
    WAITV(8)
    MIDBAR() MFMA12(1) ENDBAR()
  }

  // ---- tail iteration (K-tiles 30, 31): only (31)kh1 still to stage
  {
    RD_B(32768, 0) RD_A(0, 0, 0)
    STGA(16384, 31, 1)
    MIDBAR() MFMA12(0) ENDBAR()
    RD_A(0, 0, 1)
    STGB(49152, 31, 1)
    WAITV(8)
    MIDBAR() MFMA12(1) ENDBAR()
    RD_B(32768, 1) RD_A(0, 1, 0)
    MIDBAR() MFMA12(0) ENDBAR()
    RD_A(0, 1, 1)
    WAITV(4)
    MIDBAR() MFMA12(1) ENDBAR()
    RD_B(49152, 0) RD_A(16384, 0, 0)
    MIDBAR() MFMA12(0) ENDBAR()
    RD_A(16384, 0, 1)
    WAITV(0)
    MIDBAR() MFMA12(1) ENDBAR()
    RD_B(49152, 1) RD_A(16384, 1, 0)
    MIDBAR() MFMA12(0) ENDBAR()
    RD_A(16384, 1, 1)
    MIDBAR() MFMA12(1) ENDBAR()
  }

  // ---- epilogue. D frag: col(c) = lane&15, row(n) = (lane>>4)*4 + reg
  const int r4 = (lane >> 4) * 4;
  if (mode == 0) {
    float* outb = out + (size_t)b * CH * NT;
#pragma unroll
    for (int m = 0; m < 8; ++m) {
#pragma unroll
      for (int nf = 0; nf < 3; ++nf) {
        const int c = c0 + wc * 48 + nf * 16 + (lane & 15);
        const int o = c / 12;
        const int t = c - o * 12;
#pragma unroll
        for (int r = 0; r < 4; ++r) {
          const int n = n0 + wr * 128 + m * 16 + r4 + r;
          outb[((size_t)(ochan_base + o) * N_ + n) * T_ + t] = leaky(acc[m][nf][r]);
        }
      }
    }
  } else {
    unsigned short* Hb = Ht + (size_t)b * C_ * N_;
#pragma unroll
    for (int m = 0; m < 8; ++m) {
#pragma unroll
      for (int nf = 0; nf < 3; ++nf) {
        const int c = c0 + wc * 48 + nf * 16 + (lane & 15);
        const int nb = n0 + wr * 128 + m * 16 + r4;
        ushort4 u;
        u.x = f2bf(acc[m][nf][0]);
        u.y = f2bf(acc[m][nf][1]);
        u.z = f2bf(acc[m][nf][2]);
        u.w = f2bf(acc[m][nf][3]);
        *reinterpret_cast<ushort4*>(&Hb[(size_t)c * N_ + nb]) = u;
      }
    }
  }
#undef STGA
#undef STGB
#undef RD_B
#undef RD_A
#undef MFMA12
#undef MIDBAR
#undef ENDBAR
#undef WAITV
#undef WAITV_
}

// ---------------------------------------------------------------------------
// Workspace layout (bytes):
//   adjb : [0, 67108864)            8*2048*2048 bf16
//   R1   : [67108864, 92274688)     Xt, then Y2t   (8*768*2048 bf16)
//   R2   : [92274688, 117440512)    Yt
//   rs1  : [117440512, 117506048)   8*2048 fp32
//   rs2  : [117506048, 117571584)   8*2048 fp32
// ---------------------------------------------------------------------------
extern "C" void kernel_launch(void* const* d_in, const int* in_sizes, int n_in,
                              void* d_out, int out_size, void* d_ws, size_t ws_size,
                              hipStream_t stream) {
  const float* x   = (const float*)d_in[0];
  const float* adj = (const float*)d_in[1];
  const float* W0  = (const float*)d_in[2];
  const float* b0  = (const float*)d_in[3];
  const float* W1  = (const float*)d_in[4];
  const float* b1  = (const float*)d_in[5];
  const float* W2  = (const float*)d_in[6];
  const float* b2  = (const float*)d_in[7];
  float* out = (float*)d_out;

  char* ws = (char*)d_ws;
  unsigned short* adjb = (unsigned short*)ws;
  unsigned short* R1   = (unsigned short*)(ws + 67108864);   // Xt -> Y2t
  unsigned short* R2   = (unsigned short*)(ws + 92274688);   // Yt
  float* rs1 = (float*)(ws + 117440512);
  float* rs2 = (float*)(ws + 117506048);

  hipFuncSetAttribute((const void*)gemm8_k,
                      hipFuncAttributeMaxDynamicSharedMemorySize, 131072);

  // 1) adj -> bf16 + rowsums rs1
  hipLaunchKernelGGL(convert_rs_k, dim3(B_ * N_), dim3(256), 0, stream,
                     adj, adjb, rs1);

  // 2) x -> Xt bf16 [(f,t)][n]   (the ONLY read of x)
  hipLaunchKernelGGL(convertX_k, dim3(N_ / 256, F_, B_), dim3(256), 0, stream,
                     x, R1);

  // 3) p=0: out[0:64) = leaky(X.W0 + b0)  -- from Xt, rs=1
  hipLaunchKernelGGL(pT_k, dim3(N_ / 16, B_), dim3(256), 0, stream,
                     R1, W0, b0, (const float*)nullptr, out, 0);

  // 4) Yt = (A @ X)^T
  hipLaunchKernelGGL(gemm8_k, dim3(256), dim3(512), 131072, stream,
                     adjb, R1, out, R2, 1, 0);

  // 5) rs2 = A @ rs1
  hipLaunchKernelGGL(rs2_k, dim3(B_ * N_), dim3(256), 0, stream,
                     adjb, rs1, rs2);

  // 6) p=1: out[64:128) = leaky(Y.W1 + rs1*b1)
  hipLaunchKernelGGL(pT_k, dim3(N_ / 16, B_), dim3(256), 0, stream,
                     R2, W1, b1, rs1, out, 64);

  // 7) Y2t = (A @ Y)^T
  hipLaunchKernelGGL(gemm8_k, dim3(256), dim3(512), 131072, stream,
                     adjb, R2, out, R1, 1, 0);

  // 8) p=2: out[128:192) = leaky(Y2.W2 + rs2*b2)
  hipLaunchKernelGGL(pT_k, dim3(N_ / 16, B_), dim3(256), 0, stream,
                     R1, W2, b2, rs2, out, 128);
}

// Round 19
// 259.019 us; speedup vs baseline: 1.1615x; 1.0558x over previous
//
#include <hip/hip_runtime.h>

// Problem constants
#define B_ 8
#define N_ 2048
#define T_ 12
#define F_ 64
#define NT 24576    // N_*T_
#define CH 192      // 3 * 64 output channels
#define C_ 768      // 64 * 12 rows per diffusion GEMM B-operand

typedef __bf16 bf16x8 __attribute__((ext_vector_type(8)));
typedef float f32x4 __attribute__((ext_vector_type(4)));

typedef const __attribute__((address_space(1))) unsigned int as1_uint;
typedef __attribute__((address_space(3))) unsigned int as3_uint;

__device__ __forceinline__ void gload16(const void* g, void* l) {
  __builtin_amdgcn_global_load_lds((as1_uint*)g, (as3_uint*)l, 16, 0, 0);
}

__device__ __forceinline__ unsigned short f2bf(float f) {
  unsigned int u = __float_as_uint(f);
  u += 0x7FFFu + ((u >> 16) & 1u);   // RNE
  return (unsigned short)(u >> 16);
}

__device__ __forceinline__ float bf2f(unsigned short u) {
  return __uint_as_float(((unsigned int)u) << 16);
}

__device__ __forceinline__ float leaky(float v) {
  return v >= 0.0f ? v : 0.01f * v;
}

// ---------------------------------------------------------------------------
// convert_rs_k: adj fp32 -> adjb bf16 (row-major) AND rs1[b][n] = rowsum(adj).
// ---------------------------------------------------------------------------
__global__ __launch_bounds__(256) void convert_rs_k(const float* __restrict__ adj,
                                                    unsigned short* __restrict__ adjb,
                                                    float* __restrict__ rs1) {
  const int row = blockIdx.x;               // b*2048 + n
  const int tid = threadIdx.x;
  const int lane = tid & 63;
  const int wave = tid >> 6;
  const float4* src = reinterpret_cast<const float4*>(adj + (size_t)row * N_);
  ushort4* dst = reinterpret_cast<ushort4*>(adjb + (size_t)row * N_);

  float s = 0.0f;
#pragma unroll
  for (int i = tid; i < 512; i += 256) {
    const float4 v = src[i];
    ushort4 u;
    u.x = f2bf(v.x); u.y = f2bf(v.y); u.z = f2bf(v.z); u.w = f2bf(v.w);
    dst[i] = u;
    s += v.x + v.y + v.z + v.w;
  }
#pragma unroll
  for (int o = 32; o; o >>= 1) s += __shfl_xor(s, o);
  __shared__ float red[4];
  if (lane == 0) red[wave] = s;
  __syncthreads();
  if (tid == 0) rs1[row] = red[0] + red[1] + red[2] + red[3];
}

// ---------------------------------------------------------------------------
// rs2_k: rs2 = adjb @ rs1 (per-batch GEMV).
// ---------------------------------------------------------------------------
__global__ __launch_bounds__(256) void rs2_k(const unsigned short* __restrict__ adjb,
                                             const float* __restrict__ rs1,
                                             float* __restrict__ rs2) {
  const int row = blockIdx.x;
  const int b = row >> 11;
  const int tid = threadIdx.x;
  const int lane = tid & 63;
  const int wave = tid >> 6;
  const ushort4* src = reinterpret_cast<const ushort4*>(adjb + (size_t)row * N_);
  const float* r1 = rs1 + ((size_t)b << 11);

  float s = 0.0f;
#pragma unroll
  for (int i = tid; i < 512; i += 256) {
    const ushort4 a = src[i];
    const int m = i * 4;
    s += bf2f(a.x) * r1[m] + bf2f(a.y) * r1[m + 1]
       + bf2f(a.z) * r1[m + 2] + bf2f(a.w) * r1[m + 3];
  }
#pragma unroll
  for (int o = 32; o; o >>= 1) s += __shfl_xor(s, o);
  __shared__ float red[4];
  if (lane == 0) red[wave] = s;
  __syncthreads();
  if (tid == 0) rs2[row] = red[0] + red[1] + red[2] + red[3];
}

// ---------------------------------------------------------------------------
// convertX_k: x fp32 [b][f][n][t] -> Xt bf16 [b][(f*12+t)][n].
// ---------------------------------------------------------------------------
__global__ __launch_bounds__(256) void convertX_k(const float* __restrict__ x,
                                                  unsigned short* __restrict__ Xt) {
  __shared__ float xl[T_][260];
  const int tid = threadIdx.x;
  const int n0 = blockIdx.x * 256;
  const int f = blockIdx.y;
  const int b = blockIdx.z;

  const float* src = x + (((size_t)b * F_ + f) * N_ + n0 + tid) * T_;
  float4 v0 = *reinterpret_cast<const float4*>(src);
  float4 v1 = *reinterpret_cast<const float4*>(src + 4);
  float4 v2 = *reinterpret_cast<const float4*>(src + 8);
  xl[0][tid] = v0.x;  xl[1][tid] = v0.y;  xl[2][tid] = v0.z;  xl[3][tid] = v0.w;
  xl[4][tid] = v1.x;  xl[5][tid] = v1.y;  xl[6][tid] = v1.z;  xl[7][tid] = v1.w;
  xl[8][tid] = v2.x;  xl[9][tid] = v2.y;  xl[10][tid] = v2.z; xl[11][tid] = v2.w;
  __syncthreads();
#pragma unroll
  for (int t = 0; t < T_; ++t)
    Xt[((size_t)b * C_ + f * T_ + t) * N_ + n0 + tid] = f2bf(xl[t][tid]);
}

// ---------------------------------------------------------------------------
// stage_wt: W [64 f][64 o] fp32 -> Wt[o][f] bf16 (rows padded to 72) in LDS.
// ---------------------------------------------------------------------------
__device__ __forceinline__ void stage_wt(const float* __restrict__ W,
                                         unsigned short* Wt, int tid) {
  const int f = tid >> 2;
  const int q = tid & 3;
  const float4* row = reinterpret_cast<const float4*>(W + f * 64 + q * 16);
#pragma unroll
  for (int v4 = 0; v4 < 4; ++v4) {
    float4 v = row[v4];
    const int ob = q * 16 + v4 * 4;
    Wt[(ob + 0) * 72 + f] = f2bf(v.x);
    Wt[(ob + 1) * 72 + f] = f2bf(v.y);
    Wt[(ob + 2) * 72 + f] = f2bf(v.z);
    Wt[(ob + 3) * 72 + f] = f2bf(v.w);
  }
}

// ---------------------------------------------------------------------------
// p0_k: out[:, 0:64] = leaky(x . W0 + b0)  via MFMA, reading x directly
// (measured faster than the Xt-based path: R14 263.2 vs R17 276.0).
// ---------------------------------------------------------------------------
__global__ __launch_bounds__(256) void p0_k(const float* __restrict__ x,
                                            const float* __restrict__ W0,
                                            const float* __restrict__ bia0,
                                            float* __restrict__ out) {
  __shared__ unsigned short Wt[64 * 72];
  __shared__ float bias[64];
  const int tid = threadIdx.x;
  stage_wt(W0, Wt, tid);
  if (tid < 64) bias[tid] = bia0[tid];
  __syncthreads();

  const int lane = tid & 63;
  const int wave = tid >> 6;
  const int b = blockIdx.y;
  const int e = blockIdx.x * 64 + wave * 16 + (lane & 15);
  const int fgrp = (lane >> 4) * 8;
  const float* xb = x + (size_t)b * F_ * NT;

  bf16x8 xf[2];
#pragma unroll
  for (int kf = 0; kf < 2; ++kf)
#pragma unroll
    for (int j = 0; j < 8; ++j)
      xf[kf][j] = (__bf16)xb[(size_t)(fgrp + kf * 32 + j) * NT + e];

  float* outb = out + (size_t)b * CH * NT;
#pragma unroll
  for (int ob = 0; ob < 4; ++ob) {
    f32x4 acc = {};
#pragma unroll
    for (int kf = 0; kf < 2; ++kf) {
      bf16x8 af = *reinterpret_cast<const bf16x8*>(
          &Wt[(ob * 16 + (lane & 15)) * 72 + kf * 32 + fgrp]);
      acc = __builtin_amdgcn_mfma_f32_16x16x32_bf16(af, xf[kf], acc, 0, 0, 0);
    }
#pragma unroll
    for (int r = 0; r < 4; ++r) {
      const int o = ob * 16 + (lane >> 4) * 4 + r;
      outb[(size_t)o * NT + e] = leaky(acc[r] + bias[o]);
    }
  }
}

// ---------------------------------------------------------------------------
// pT_k: out[ocb..ocb+64) = leaky(Y.W + rs*b), Y given as Yt bf16 [(f*12+t)][n].
// ---------------------------------------------------------------------------
__global__ __launch_bounds__(256) void pT_k(const unsigned short* __restrict__ Yt,
                                            const float* __restrict__ W,
                                            const float* __restrict__ bia,
                                            const float* __restrict__ rs,
                                            float* __restrict__ out,
                                            const int ocb) {
  __shared__ unsigned short Wt[64 * 72];
  __shared__ float bias[64];
  const int tid = threadIdx.x;
  stage_wt(W, Wt, tid);
  if (tid < 64) bias[tid] = bia[tid];
  __syncthreads();

  const int lane = tid & 63;
  const int wave = tid >> 6;
  const int b = blockIdx.y;
  const int n = blockIdx.x * 16 + (lane & 15);
  const int fgrp = (lane >> 4) * 8;
  const __bf16* Yb = reinterpret_cast<const __bf16*>(Yt + (size_t)b * C_ * N_);
  const float rsv = rs ? rs[((size_t)b << 11) + n] : 1.0f;
  float* outb = out + (size_t)b * CH * NT;

#pragma unroll
  for (int it = 0; it < 3; ++it) {
    const int t = wave * 3 + it;

    bf16x8 xf[2];
#pragma unroll
    for (int kf = 0; kf < 2; ++kf)
#pragma unroll
      for (int j = 0; j < 8; ++j)
        xf[kf][j] = Yb[(size_t)((kf * 32 + fgrp + j) * T_ + t) * N_ + n];

#pragma unroll
    for (int ob = 0; ob < 4; ++ob) {
      f32x4 acc = {};
#pragma unroll
      for (int kf = 0; kf < 2; ++kf) {
        bf16x8 af = *reinterpret_cast<const bf16x8*>(
            &Wt[(ob * 16 + (lane & 15)) * 72 + kf * 32 + fgrp]);
        acc = __builtin_amdgcn_mfma_f32_16x16x32_bf16(af, xf[kf], acc, 0, 0, 0);
      }
#pragma unroll
      for (int r = 0; r < 4; ++r) {
        const int o = ob * 16 + (lane >> 4) * 4 + r;
        outb[(size_t)(ocb + o) * NT + n * T_ + t] = leaky(acc[r] + rsv * bias[o]);
      }
    }
  }
}

// ---------------------------------------------------------------------------
// gemm8_k (round-4 schedule, best-measured GEMM):
// 256x192 tile, BK=64 (2 kh planes of 32), 8 waves (2M x 4N), acc[8][3],
// 8 phases of 12 MFMA per K-tile pair, counted vmcnt(8) every other phase.
// LDS 128KB dynamic, granule-XOR conflict-free layout.
// grid 256 = 8 b x (8 n x 4 c); blockIdx&7 = batch = XCD.
// mode 1: Ht[c][n] = bf16(C) (transposed; feeds pT and the next GEMM).
// ---------------------------------------------------------------------------
__global__ __launch_bounds__(512, 2) void gemm8_k(
    const unsigned short* __restrict__ adjb,
    const unsigned short* __restrict__ Bt,
    float* __restrict__ out,
    unsigned short* __restrict__ Ht,
    const int mode, const int ochan_base)
{
  extern __shared__ __align__(16) unsigned short lds[];  // 65536 shorts = 128KB

  const int tid  = threadIdx.x;
  const int lane = tid & 63;
  const int wave = tid >> 6;
  const int wr = wave >> 2;      // 0..1  (M half, 128 rows)
  const int wc = wave & 3;       // 0..3  (N quarter, 48 cols)

  const int b  = blockIdx.x & 7;            // batch == XCD (round-robin)
  const int w  = blockIdx.x >> 3;           // 0..31
  const int n0 = (w & 7) * 256;
  const int c0 = (w >> 3) * 192;

  const unsigned short* A  = adjb + (size_t)b * N_ * N_;
  const unsigned short* Bm = Bt   + (size_t)b * C_ * N_;

  const int swzSrc = ((lane & 3) ^ ((lane >> 3) & 3)) * 8;   // shorts
  const unsigned short* aSt1 = A + (size_t)(n0 + wave * 16 + (lane >> 2)) * N_ + swzSrc;
  const unsigned short* aSt2 = aSt1 + (size_t)128 * N_;
  const unsigned short* bSt1 = Bm + (size_t)(c0 + wave * 16 + (lane >> 2)) * N_ + swzSrc;
  const int brow2 = c0 + 128 + wave * 16 + (lane >> 2);
  const unsigned short* bSt2 = Bm + (size_t)(brow2 < C_ ? brow2 : C_ - 1) * N_ + swzSrc;
  const int ldsW = wave * 512;

  const int kg  = (lane >> 4) ^ ((lane >> 1) & 3);
  const int aRd = (wr * 128 + (lane & 15)) * 32 + kg * 8;
  const int bRd = (wc * 48  + (lane & 15)) * 32 + kg * 8;

  f32x4 acc[8][3] = {};
  bf16x8 afr[4], bfr[3];

#define STGA(LDSB, KT, KH) \
  gload16(aSt1 + (KT) * 64 + (KH) * 32, lds + (LDSB) + (KH) * 8192 + ldsW); \
  gload16(aSt2 + (KT) * 64 + (KH) * 32, lds + (LDSB) + (KH) * 8192 + ldsW + 4096);

#define STGB(LDSB, KT, KH) \
  gload16(bSt1 + (KT) * 64 + (KH) * 32, lds + (LDSB) + (KH) * 8192 + ldsW); \
  gload16(bSt2 + (KT) * 64 + (KH) * 32, lds + (LDSB) + (KH) * 8192 + ldsW + 4096);

#define RD_B(BUFB, KH) { \
  _Pragma("unroll") \
  for (int nf = 0; nf < 3; ++nf) \
    bfr[nf] = *(const bf16x8*)(lds + (BUFB) + (KH) * 8192 + nf * 512 + bRd); }

#define RD_A(BUFA, KH, QM) { \
  _Pragma("unroll") \
  for (int mm = 0; mm < 4; ++mm) \
    afr[mm] = *(const bf16x8*)(lds + (BUFA) + (KH) * 8192 + (QM) * 2048 + mm * 512 + aRd); }

#define MFMA12(QM) { \
  _Pragma("unroll") \
  for (int mm = 0; mm < 4; ++mm) \
  _Pragma("unroll") \
  for (int nf = 0; nf < 3; ++nf) \
    acc[(QM) * 4 + mm][nf] = __builtin_amdgcn_mfma_f32_16x16x32_bf16( \
        afr[mm], bfr[nf], acc[(QM) * 4 + mm][nf], 0, 0, 0); }

#define MIDBAR() \
  __builtin_amdgcn_s_barrier(); \
  asm volatile("s_waitcnt lgkmcnt(0)" ::: "memory"); \
  __builtin_amdgcn_sched_barrier(0); \
  __builtin_amdgcn_s_setprio(1);

#define ENDBAR() \
  __builtin_amdgcn_s_setprio(0); \
  __builtin_amdgcn_s_barrier();

#define WAITV_(N) asm volatile("s_waitcnt vmcnt(" #N ")" ::: "memory");
#define WAITV(N) WAITV_(N)

  STGA(0, 0, 0)      STGB(32768, 0, 0)
  STGA(0, 0, 1)      STGB(32768, 0, 1)
  STGA(16384, 1, 0)  STGB(49152, 1, 0)
  WAITV(8)
  __builtin_amdgcn_s_barrier();

#pragma unroll 1
  for (int it = 0; it < 15; ++it) {
    const int kt0 = 2 * it;
    RD_B(32768, 0) RD_A(0, 0, 0)
    STGA(16384, kt0 + 1, 1)
    MIDBAR() MFMA12(0) ENDBAR()
    RD_A(0, 0, 1)
    STGB(49152, kt0 + 1, 1)
    WAITV(8)
    MIDBAR() MFMA12(1) ENDBAR()
    RD_B(32768, 1) RD_A(0, 1, 0)
    STGA(0, kt0 + 2, 0)
    MIDBAR() MFMA12(0) ENDBAR()
    RD_A(0, 1, 1)
    STGB(32768, kt0 + 2, 0)
    WAITV(8)
    MIDBAR() MFMA12(1) ENDBAR()
    RD_B(49152, 0) RD_A(16384, 0, 0)
    STGA(0, kt0 + 2, 1)
    MIDBAR() MFMA12(0) ENDBAR()
    RD_A(16384, 0, 1)
    STGB(32768, kt0 + 2, 1)
    WAITV(8)
    MIDBAR() MFMA12(1) ENDBAR()
    RD_B(49152, 1) RD_A(16384, 1, 0)
    STGA(16384, kt0 + 3, 0)
    MIDBAR() MFMA12(0) ENDBAR()
    RD_A(16384, 1, 1)
    STGB(49152, kt0 + 3, 0)
    WAITV(8)
    MIDBAR() MFMA12(1) ENDBAR()
  }

  {
    RD_B(32768, 0) RD_A(0, 0, 0)
    STGA(16384, 31, 1)
    MIDBAR() MFMA12(0) ENDBAR()
    RD_A(0, 0, 1)
    STGB(49152, 31, 1)
    WAITV(8)
    MIDBAR() MFMA12(1) ENDBAR()
    RD_B(32768, 1) RD_A(0, 1, 0)
    MIDBAR() MFMA12(0) ENDBAR()
    RD_A(0, 1, 1)
    WAITV(4)
    MIDBAR() MFMA12(1) ENDBAR()
    RD_B(49152, 0) RD_A(16384, 0, 0)
    MIDBAR() MFMA12(0) ENDBAR()
    RD_A(16384, 0, 1)
    WAITV(0)
    MIDBAR() MFMA12(1) ENDBAR()
    RD_B(49152, 1) RD_A(16384, 1, 0)
    MIDBAR() MFMA12(0) ENDBAR()
    RD_A(16384, 1, 1)
    MIDBAR() MFMA12(1) ENDBAR()
  }

  // ---- epilogue. D frag: col(c) = lane&15, row(n) = (lane>>4)*4 + reg
  const int r4 = (lane >> 4) * 4;
  if (mode == 0) {
    float* outb = out + (size_t)b * CH * NT;
#pragma unroll
    for (int m = 0; m < 8; ++m) {
#pragma unroll
      for (int nf = 0; nf < 3; ++nf) {
        const int c = c0 + wc * 48 + nf * 16 + (lane & 15);
        const int o = c / 12;
        const int t = c - o * 12;
#pragma unroll
        for (int r = 0; r < 4; ++r) {
          const int n = n0 + wr * 128 + m * 16 + r4 + r;
          outb[((size_t)(ochan_base + o) * N_ + n) * T_ + t] = leaky(acc[m][nf][r]);
        }
      }
    }
  } else {
    unsigned short* Hb = Ht + (size_t)b * C_ * N_;
#pragma unroll
    for (int m = 0; m < 8; ++m) {
#pragma unroll
      for (int nf = 0; nf < 3; ++nf) {
        const int c = c0 + wc * 48 + nf * 16 + (lane & 15);
        const int nb = n0 + wr * 128 + m * 16 + r4;
        ushort4 u;
        u.x = f2bf(acc[m][nf][0]);
        u.y = f2bf(acc[m][nf][1]);
        u.z = f2bf(acc[m][nf][2]);
        u.w = f2bf(acc[m][nf][3]);
        *reinterpret_cast<ushort4*>(&Hb[(size_t)c * N_ + nb]) = u;
      }
    }
  }
#undef STGA
#undef STGB
#undef RD_B
#undef RD_A
#undef MFMA12
#undef MIDBAR
#undef ENDBAR
#undef WAITV
#undef WAITV_
}

// ---------------------------------------------------------------------------
// Workspace layout (bytes):
//   adjb : [0, 67108864)            8*2048*2048 bf16
//   R1   : [67108864, 92274688)     Xt, then Y2t   (8*768*2048 bf16)
//   R2   : [92274688, 117440512)    Yt
//   rs1  : [117440512, 117506048)   8*2048 fp32
//   rs2  : [117506048, 117571584)   8*2048 fp32
// ---------------------------------------------------------------------------
extern "C" void kernel_launch(void* const* d_in, const int* in_sizes, int n_in,
                              void* d_out, int out_size, void* d_ws, size_t ws_size,
                              hipStream_t stream) {
  const float* x   = (const float*)d_in[0];
  const float* adj = (const float*)d_in[1];
  const float* W0  = (const float*)d_in[2];
  const float* b0  = (const float*)d_in[3];
  const float* W1  = (const float*)d_in[4];
  const float* b1  = (const float*)d_in[5];
  const float* W2  = (const float*)d_in[6];
  const float* b2  = (const float*)d_in[7];
  float* out = (float*)d_out;

  char* ws = (char*)d_ws;
  unsigned short* adjb = (unsigned short*)ws;
  unsigned short* R1   = (unsigned short*)(ws + 67108864);   // Xt -> Y2t
  unsigned short* R2   = (unsigned short*)(ws + 92274688);   // Yt
  float* rs1 = (float*)(ws + 117440512);
  float* rs2 = (float*)(ws + 117506048);

  hipFuncSetAttribute((const void*)gemm8_k,
                      hipFuncAttributeMaxDynamicSharedMemorySize, 131072);

  // 1) adj -> bf16 + rowsums rs1
  hipLaunchKernelGGL(convert_rs_k, dim3(B_ * N_), dim3(256), 0, stream,
                     adj, adjb, rs1);

  // 2) x -> Xt bf16 [(f,t)][n]
  hipLaunchKernelGGL(convertX_k, dim3(N_ / 256, F_, B_), dim3(256), 0, stream,
                     x, R1);

  // 3) p=0: out[0:64) = leaky(x.W0 + b0)   (direct from x — measured fastest)
  hipLaunchKernelGGL(p0_k, dim3(NT / 64, B_), dim3(256), 0, stream,
                     x, W0, b0, out);

  // 4) Yt = (A @ X)^T
  hipLaunchKernelGGL(gemm8_k, dim3(256), dim3(512), 131072, stream,
                     adjb, R1, out, R2, 1, 0);

  // 5) rs2 = A @ rs1
  hipLaunchKernelGGL(rs2_k, dim3(B_ * N_), dim3(256), 0, stream,
                     adjb, rs1, rs2);

  // 6) p=1: out[64:128) = leaky(Y.W1 + rs1*b1)
  hipLaunchKernelGGL(pT_k, dim3(N_ / 16, B_), dim3(256), 0, stream,
                     R2, W1, b1, rs1, out, 64);

  // 7) Y2t = (A @ Y)^T
  hipLaunchKernelGGL(gemm8_k, dim3(256), dim3(512), 131072, stream,
                     adjb, R2, out, R1, 1, 0);

  // 8) p=2: out[128:192) = leaky(Y2.W2 + rs2*b2)
  hipLaunchKernelGGL(pT_k, dim3(N_ / 16, B_), dim3(256), 0, stream,
                     R1, W2, b2, rs2, out, 128);
}